// Round 3
// baseline (386.630 us; speedup 1.0000x reference)
//
#include <hip/hip_runtime.h>
#include <hip/hip_cooperative_groups.h>
#include <math.h>

namespace cg = cooperative_groups;

// Pair-embedding scorer; 4 stacked Linears with no activation => one affine map.
// Fold: v4=W4[:,0]; v3=W3@v4; v2=W2@v3; v1=W1@v2; c=b4+b3.v4+b2.v3+b1.v2
// Then sA[e]=feature[e].v1[:901], sB[e]=feature[e].v1[901:],
// out[i]=sigmoid(sA[p0]+sB[p1]+c).
//
// Primary path: ONE cooperative kernel, grid.sync between stages.
//   512 blocks x 256 thr, __launch_bounds__(256,2): 2 blocks/CU needed, >=4 fit
//   -> 2x margin against hipErrorCooperativeLaunchTooLarge (round-2 failure).
// Fallback (if coop launch returns error): 5 plain launches of the same stages.
//
// ws layout (floats): [0,512) v3 | [512,1536) v2 | [1536,3338) v1 | [3400] c
//                     [4096,24096) sA | [24096,44096) sB

#define NBLK 512
#define NTHR 256

__device__ inline float wave_reduce_sum(float v) {
    #pragma unroll
    for (int off = 32; off; off >>= 1) v += __shfl_down(v, off, 64);
    return v;
}

// ---- Stage A: v3 = W3@v4 (512 rows, K=64); wave 512: c = b4 + b3.v4 ----
__device__ inline void stageA(const float* __restrict__ W3, const float* __restrict__ b3,
                              const float* __restrict__ W4, const float* __restrict__ b4,
                              float* __restrict__ v3, float* __restrict__ c,
                              int gwave, int lane) {
    if (gwave > 512) return;
    float x = W4[lane];
    if (gwave == 512) {
        float acc = wave_reduce_sum(b3[lane] * x);
        if (lane == 0) *c = *b4 + acc;
    } else {
        float acc = wave_reduce_sum(W3[(size_t)gwave * 64 + lane] * x);
        if (lane == 0) v3[gwave] = acc;
    }
}

// ---- Stage B: v2 = W2@v3 (1024 rows, K=512, float4); wave 1024: c += b2.v3 ----
__device__ inline void stageB(const float* __restrict__ W2, const float* __restrict__ b2,
                              const float* __restrict__ v3, float* __restrict__ v2,
                              float* __restrict__ c, int gwave, int lane) {
    if (gwave > 1024) return;
    if (gwave == 1024) {
        float acc = 0.f;
        for (int k = lane; k < 512; k += 64) acc += b2[k] * v3[k];
        acc = wave_reduce_sum(acc);
        if (lane == 0) *c += acc;
    } else {
        const float4* row4 = (const float4*)(W2 + (size_t)gwave * 512);
        const float4* x4   = (const float4*)v3;
        float acc = 0.f;
        #pragma unroll
        for (int it = 0; it < 2; ++it) {
            float4 w = row4[lane + 64 * it];
            float4 x = x4[lane + 64 * it];
            acc += w.x * x.x + w.y * x.y + w.z * x.z + w.w * x.w;
        }
        acc = wave_reduce_sum(acc);
        if (lane == 0) v2[gwave] = acc;
    }
}

// ---- Stage C: v1 = W1@v2 (1802 rows, K=1024, float4); wave 1802: c += b1.v2 ----
__device__ inline void stageC(const float* __restrict__ W1, const float* __restrict__ b1,
                              const float* __restrict__ v2, float* __restrict__ v1,
                              float* __restrict__ c, int gwave, int lane) {
    if (gwave > 1802) return;
    if (gwave == 1802) {
        float acc = 0.f;
        for (int k = lane; k < 1024; k += 64) acc += b1[k] * v2[k];
        acc = wave_reduce_sum(acc);
        if (lane == 0) *c += acc;
    } else {
        const float4* row4 = (const float4*)(W1 + (size_t)gwave * 1024);
        const float4* x4   = (const float4*)v2;
        float acc = 0.f;
        #pragma unroll
        for (int it = 0; it < 4; ++it) {
            float4 w = row4[lane + 64 * it];
            float4 x = x4[lane + 64 * it];
            acc += w.x * x.x + w.y * x.y + w.z * x.z + w.w * x.w;
        }
        acc = wave_reduce_sum(acc);
        if (lane == 0) v1[gwave] = acc;
    }
}

// ---- Stage D: per-entity half-dots over the 72 MB feature stream (float4) ----
__device__ inline void stageD(const float* __restrict__ F, const float* __restrict__ v1,
                              float* __restrict__ sA, float* __restrict__ sB,
                              int NE, int D, int gwave, int lane, int nwave) {
    const float* va = v1;
    const float* vb = v1 + D;
    // Row stride nwave is a multiple of 4 and D%4==1 -> alignment phase is
    // constant per wave; the v1 coefficients each lane needs are fixed.
    const int a0   = (4 - (gwave & 3)) & 3;
    const int nvec = (D - a0) >> 2;
    const int rem  = (D - a0) & 3;

    float ca[16], cb[16];
    #pragma unroll
    for (int it = 0; it < 4; ++it) {
        int vi = lane + 64 * it;
        int d  = a0 + 4 * vi;
        bool ok = vi < nvec;
        ca[4*it+0] = ok ? va[d+0] : 0.f;  cb[4*it+0] = ok ? vb[d+0] : 0.f;
        ca[4*it+1] = ok ? va[d+1] : 0.f;  cb[4*it+1] = ok ? vb[d+1] : 0.f;
        ca[4*it+2] = ok ? va[d+2] : 0.f;  cb[4*it+2] = ok ? vb[d+2] : 0.f;
        ca[4*it+3] = ok ? va[d+3] : 0.f;  cb[4*it+3] = ok ? vb[d+3] : 0.f;
    }
    float cpa = (lane < a0) ? va[lane] : 0.f;
    float cpb = (lane < a0) ? vb[lane] : 0.f;
    int   dt  = a0 + 4 * nvec + lane;
    float cta = (lane < rem) ? va[dt] : 0.f;
    float ctb = (lane < rem) ? vb[dt] : 0.f;

    for (int row = gwave; row < NE; row += nwave) {
        const float* p = F + (size_t)row * (size_t)D;
        float a = 0.f, b = 0.f;
        if (lane < a0) { float f = p[lane]; a = f * cpa; b = f * cpb; }
        const float4* p4 = (const float4*)(p + a0);
        #pragma unroll
        for (int it = 0; it < 4; ++it) {
            int vi = lane + 64 * it;
            if (vi < nvec) {
                float4 f = p4[vi];
                a += f.x * ca[4*it+0] + f.y * ca[4*it+1]
                   + f.z * ca[4*it+2] + f.w * ca[4*it+3];
                b += f.x * cb[4*it+0] + f.y * cb[4*it+1]
                   + f.z * cb[4*it+2] + f.w * cb[4*it+3];
            }
        }
        if (lane < rem) { float f = p[a0 + 4 * nvec + lane]; a += f * cta; b += f * ctb; }
        a = wave_reduce_sum(a);
        b = wave_reduce_sum(b);
        if (lane == 0) { sA[row] = a; sB[row] = b; }
    }
}

// ---- Stage E: out[i] = sigmoid(sA[p0] + sB[p1] + c), grid-stride ----
__device__ inline void stageE(const int* __restrict__ tr, const int* __restrict__ te,
                              const float* __restrict__ sA, const float* __restrict__ sB,
                              const float* __restrict__ c, float* __restrict__ out,
                              int NTR, int NTE, int tid, int nthreads) {
    const float cc = *c;
    const int n = NTR + NTE;
    for (int i = tid; i < n; i += nthreads) {
        int2 pr;
        if (i < NTR) pr = ((const int2*)tr)[i];
        else         pr = ((const int2*)te)[i - NTR];
        float x = sA[pr.x] + sB[pr.y] + cc;
        out[i] = 1.0f / (1.0f + __expf(-x));
    }
}

// ================= primary: one cooperative kernel =================
__global__ __launch_bounds__(NTHR, 2)
void fused(const float* __restrict__ F,
           const float* __restrict__ W1, const float* __restrict__ b1,
           const float* __restrict__ W2, const float* __restrict__ b2,
           const float* __restrict__ W3, const float* __restrict__ b3,
           const float* __restrict__ W4, const float* __restrict__ b4,
           const int* __restrict__ tr, const int* __restrict__ te,
           float* __restrict__ out, float* __restrict__ ws,
           int NE, int D, int NTR, int NTE)
{
    cg::grid_group grid = cg::this_grid();
    float* v3 = ws;       float* v2 = ws + 512;  float* v1 = ws + 1536;
    float* c  = ws + 3400; float* sA = ws + 4096; float* sB = ws + 24096;

    const int tid      = blockIdx.x * blockDim.x + threadIdx.x;
    const int nthreads = gridDim.x * blockDim.x;
    const int gwave    = tid >> 6;
    const int nwave    = nthreads >> 6;
    const int lane     = tid & 63;

    stageA(W3, b3, W4, b4, v3, c, gwave, lane);
    grid.sync();
    stageB(W2, b2, v3, v2, c, gwave, lane);
    grid.sync();
    stageC(W1, b1, v2, v1, c, gwave, lane);
    grid.sync();
    stageD(F, v1, sA, sB, NE, D, gwave, lane, nwave);
    grid.sync();
    stageE(tr, te, sA, sB, c, out, NTR, NTE, tid, nthreads);
}

// ================= fallback: five plain kernels =================
__global__ __launch_bounds__(NTHR, 2)
void kA(const float* W3, const float* b3, const float* W4, const float* b4,
        float* v3, float* c) {
    int tid = blockIdx.x * blockDim.x + threadIdx.x;
    stageA(W3, b3, W4, b4, v3, c, tid >> 6, tid & 63);
}
__global__ __launch_bounds__(NTHR, 2)
void kB(const float* W2, const float* b2, const float* v3, float* v2, float* c) {
    int tid = blockIdx.x * blockDim.x + threadIdx.x;
    stageB(W2, b2, v3, v2, c, tid >> 6, tid & 63);
}
__global__ __launch_bounds__(NTHR, 2)
void kC(const float* W1, const float* b1, const float* v2, float* v1, float* c) {
    int tid = blockIdx.x * blockDim.x + threadIdx.x;
    stageC(W1, b1, v2, v1, c, tid >> 6, tid & 63);
}
__global__ __launch_bounds__(NTHR, 2)
void kD(const float* F, const float* v1, float* sA, float* sB, int NE, int D) {
    int tid = blockIdx.x * blockDim.x + threadIdx.x;
    stageD(F, v1, sA, sB, NE, D, tid >> 6, tid & 63, (gridDim.x * blockDim.x) >> 6);
}
__global__ __launch_bounds__(NTHR, 2)
void kE(const int* tr, const int* te, const float* sA, const float* sB,
        const float* c, float* out, int NTR, int NTE) {
    int tid = blockIdx.x * blockDim.x + threadIdx.x;
    stageE(tr, te, sA, sB, c, out, NTR, NTE, tid, gridDim.x * blockDim.x);
}

extern "C" void kernel_launch(void* const* d_in, const int* in_sizes, int n_in,
                              void* d_out, int out_size, void* d_ws, size_t ws_size,
                              hipStream_t stream) {
    const float* F  = (const float*)d_in[0];
    const float* W1 = (const float*)d_in[1];
    const float* b1 = (const float*)d_in[2];
    const float* W2 = (const float*)d_in[3];
    const float* b2 = (const float*)d_in[4];
    const float* W3 = (const float*)d_in[5];
    const float* b3 = (const float*)d_in[6];
    const float* W4 = (const float*)d_in[7];
    const float* b4 = (const float*)d_in[8];
    const int*   tr = (const int*)d_in[9];
    const int*   te = (const int*)d_in[10];
    float*       out = (float*)d_out;
    float*       ws  = (float*)d_ws;

    int NE = 20000, D = 901;
    int NTR = in_sizes[9] / 2;
    int NTE = in_sizes[10] / 2;

    void* args[] = { (void*)&F, (void*)&W1, (void*)&b1, (void*)&W2, (void*)&b2,
                     (void*)&W3, (void*)&b3, (void*)&W4, (void*)&b4,
                     (void*)&tr, (void*)&te, (void*)&out, (void*)&ws,
                     (void*)&NE, (void*)&D, (void*)&NTR, (void*)&NTE };
    hipError_t err = hipLaunchCooperativeKernel((const void*)fused, dim3(NBLK),
                                                dim3(NTHR), args, 0, stream);
    if (err != hipSuccess) {
        (void)hipGetLastError();  // clear sticky error, take the plain path
        float* v3 = ws;        float* v2 = ws + 512;  float* v1 = ws + 1536;
        float* c  = ws + 3400; float* sA = ws + 4096; float* sB = ws + 24096;
        kA<<<129, NTHR, 0, stream>>>(W3, b3, W4, b4, v3, c);
        kB<<<257, NTHR, 0, stream>>>(W2, b2, v3, v2, c);
        kC<<<451, NTHR, 0, stream>>>(W1, b1, v2, v1, c);
        kD<<<NBLK, NTHR, 0, stream>>>(F, v1, sA, sB, NE, D);
        kE<<<NBLK, NTHR, 0, stream>>>(tr, te, sA, sB, c, out, NTR, NTE);
    }
}

// Round 4
// 213.385 us; speedup vs baseline: 1.8119x; 1.8119x over previous
//
#include <hip/hip_runtime.h>
#include <math.h>

// Pair-embedding scorer; 4 stacked Linears, no activation => one affine map.
//   v4 = W4[:,0]; v3 = W3@v4; v2 = W2@v3; v1 = W1@v2
//   c  = b4 + b3.v4 + b2.v3 + b1.v2
//   sA[e] = feature[e] . v1[:901];  sB[e] = feature[e] . v1[901:]
//   out[i] = sigmoid(sA[p0] + sB[p1] + c)
//
// Round-3 lesson: cg::grid.sync() costs ~60 us each on gfx950 (cross-XCD
// fence + sleep spin) -> 264 us at VALUBusy 0.9%. Plain sequential launches
// on one stream give the same inter-stage coherence for ~2-3 us each.
//
// 4 launches: kAB (v3 in LDS + v2 + c), kC (v1), kD (72 MB stream), kE (head).
//
// ws layout (floats): [512,1536) v2 | [1536,3338) v1 | [3400] c
//                     [4096,24096) sA | [24096,44096) sB

#define NTHR 256

__device__ inline float wave_reduce_sum(float v) {
    #pragma unroll
    for (int off = 32; off; off >>= 1) v += __shfl_down(v, off, 64);
    return v;
}

// ---- kAB: 16 blocks. Each block computes ALL of v3 (tiny, redundant, LDS)
// then its own 64-row slice of v2. Block 0 wave 0 also writes c (partial). ----
__global__ __launch_bounds__(NTHR)
void kAB(const float* __restrict__ W2, const float* __restrict__ b2,
         const float* __restrict__ W3, const float* __restrict__ b3,
         const float* __restrict__ W4, const float* __restrict__ b4,
         float* __restrict__ v2, float* __restrict__ c) {
    __shared__ float s_v3[512];
    __shared__ float s_v4[64];
    const int t = threadIdx.x, wave = t >> 6, lane = t & 63;
    if (t < 64) s_v4[t] = W4[t];
    __syncthreads();
    const float x = s_v4[lane];
    // full v3 per block: wave-per-row, coalesced W3 reads (131 KB, L2-hot)
    for (int r = wave; r < 512; r += 4) {
        float acc = wave_reduce_sum(W3[(size_t)r * 64 + lane] * x);
        if (lane == 0) s_v3[r] = acc;
    }
    __syncthreads();
    // this block's 64 rows of v2, float4 row loads vs LDS v3
    const int row0 = blockIdx.x * 64;
    const float4* x4 = (const float4*)s_v3;
    for (int r = wave; r < 64; r += 4) {
        const int row = row0 + r;
        const float4* w4p = (const float4*)(W2 + (size_t)row * 512);
        float acc = 0.f;
        #pragma unroll
        for (int it = 0; it < 2; ++it) {
            float4 w  = w4p[lane + 64 * it];
            float4 xx = x4[lane + 64 * it];
            acc += w.x * xx.x + w.y * xx.y + w.z * xx.z + w.w * xx.w;
        }
        acc = wave_reduce_sum(acc);
        if (lane == 0) v2[row] = acc;
    }
    // c = b4 + b3.v4 + b2.v3   (b1.v2 added by kC via atomicAdd)
    if (blockIdx.x == 0 && wave == 0) {
        float acc = b3[lane] * x;
        for (int k = lane; k < 512; k += 64) acc += b2[k] * s_v3[k];
        acc = wave_reduce_sum(acc);
        if (lane == 0) *c = *b4 + acc;
    }
}

// ---- kC: v1 = W1 @ v2 (1802 rows, K=1024, float4); wave 1802: c += b1.v2 ----
__global__ __launch_bounds__(NTHR)
void kC(const float* __restrict__ W1, const float* __restrict__ b1,
        const float* __restrict__ v2, float* __restrict__ v1,
        float* __restrict__ c) {
    const int tid = blockIdx.x * blockDim.x + threadIdx.x;
    const int gwave = tid >> 6, lane = tid & 63;
    if (gwave > 1802) return;
    if (gwave == 1802) {
        float acc = 0.f;
        for (int k = lane; k < 1024; k += 64) acc += b1[k] * v2[k];
        acc = wave_reduce_sum(acc);
        if (lane == 0) atomicAdd(c, acc);
        return;
    }
    const float4* row4 = (const float4*)(W1 + (size_t)gwave * 1024);
    const float4* x4   = (const float4*)v2;
    float acc = 0.f;
    #pragma unroll
    for (int it = 0; it < 4; ++it) {
        float4 w = row4[lane + 64 * it];
        float4 x = x4[lane + 64 * it];
        acc += w.x * x.x + w.y * x.y + w.z * x.z + w.w * x.w;
    }
    acc = wave_reduce_sum(acc);
    if (lane == 0) v1[gwave] = acc;
}

// ---- kD: per-entity half-dots over the 72 MB feature stream (float4).
// Grid-stride (nwave % 4 == 0, D % 4 == 1 -> per-wave alignment phase is
// constant, so each lane's v1 coefficients are fixed and preloaded once). ----
__global__ __launch_bounds__(NTHR)
void kD(const float* __restrict__ F, const float* __restrict__ v1,
        float* __restrict__ sA, float* __restrict__ sB, int NE, int D) {
    const int tid   = blockIdx.x * blockDim.x + threadIdx.x;
    const int gwave = tid >> 6, lane = tid & 63;
    const int nwave = (gridDim.x * blockDim.x) >> 6;
    const float* va = v1;
    const float* vb = v1 + D;
    const int a0   = (4 - (gwave & 3)) & 3;   // scalars to 16B boundary
    const int nvec = (D - a0) >> 2;
    const int rem  = (D - a0) & 3;

    float ca[16], cb[16];
    #pragma unroll
    for (int it = 0; it < 4; ++it) {
        int vi = lane + 64 * it;
        int d  = a0 + 4 * vi;
        bool ok = vi < nvec;
        ca[4*it+0] = ok ? va[d+0] : 0.f;  cb[4*it+0] = ok ? vb[d+0] : 0.f;
        ca[4*it+1] = ok ? va[d+1] : 0.f;  cb[4*it+1] = ok ? vb[d+1] : 0.f;
        ca[4*it+2] = ok ? va[d+2] : 0.f;  cb[4*it+2] = ok ? vb[d+2] : 0.f;
        ca[4*it+3] = ok ? va[d+3] : 0.f;  cb[4*it+3] = ok ? vb[d+3] : 0.f;
    }
    float cpa = (lane < a0) ? va[lane] : 0.f;
    float cpb = (lane < a0) ? vb[lane] : 0.f;
    int   dt  = a0 + 4 * nvec + lane;
    float cta = (lane < rem) ? va[dt] : 0.f;
    float ctb = (lane < rem) ? vb[dt] : 0.f;

    for (int row = gwave; row < NE; row += nwave) {
        const float* p = F + (size_t)row * (size_t)D;
        float a = 0.f, b = 0.f;
        if (lane < a0) { float f = p[lane]; a = f * cpa; b = f * cpb; }
        const float4* p4 = (const float4*)(p + a0);
        #pragma unroll
        for (int it = 0; it < 4; ++it) {
            int vi = lane + 64 * it;
            if (vi < nvec) {
                float4 f = p4[vi];
                a += f.x * ca[4*it+0] + f.y * ca[4*it+1]
                   + f.z * ca[4*it+2] + f.w * ca[4*it+3];
                b += f.x * cb[4*it+0] + f.y * cb[4*it+1]
                   + f.z * cb[4*it+2] + f.w * cb[4*it+3];
            }
        }
        if (lane < rem) { float f = p[a0 + 4 * nvec + lane]; a += f * cta; b += f * ctb; }
        a = wave_reduce_sum(a);
        b = wave_reduce_sum(b);
        if (lane == 0) { sA[row] = a; sB[row] = b; }
    }
}

// ---- kE: out[i] = sigmoid(sA[p0] + sB[p1] + c) ----
__global__ __launch_bounds__(NTHR)
void kE(const int* __restrict__ tr, const int* __restrict__ te,
        const float* __restrict__ sA, const float* __restrict__ sB,
        const float* __restrict__ c, float* __restrict__ out,
        int NTR, int NTE) {
    const int i = blockIdx.x * blockDim.x + threadIdx.x;
    const int n = NTR + NTE;
    if (i >= n) return;
    int2 pr;
    if (i < NTR) pr = ((const int2*)tr)[i];
    else         pr = ((const int2*)te)[i - NTR];
    float x = sA[pr.x] + sB[pr.y] + *c;      // sA/sB = 160 KB, L2-resident
    out[i] = 1.0f / (1.0f + __expf(-x));
}

extern "C" void kernel_launch(void* const* d_in, const int* in_sizes, int n_in,
                              void* d_out, int out_size, void* d_ws, size_t ws_size,
                              hipStream_t stream) {
    const float* F  = (const float*)d_in[0];
    const float* W1 = (const float*)d_in[1];
    const float* b1 = (const float*)d_in[2];
    const float* W2 = (const float*)d_in[3];
    const float* b2 = (const float*)d_in[4];
    const float* W3 = (const float*)d_in[5];
    const float* b3 = (const float*)d_in[6];
    const float* W4 = (const float*)d_in[7];
    const float* b4 = (const float*)d_in[8];
    const int*   tr = (const int*)d_in[9];
    const int*   te = (const int*)d_in[10];
    float*       out = (float*)d_out;
    float*       ws  = (float*)d_ws;

    const int NE = 20000, D = 901;
    const int NTR = in_sizes[9] / 2;    // 100000
    const int NTE = in_sizes[10] / 2;   // 25000

    float* v2 = ws + 512;
    float* v1 = ws + 1536;
    float* c  = ws + 3400;
    float* sA = ws + 4096;
    float* sB = ws + 24096;

    kAB<<<16, NTHR, 0, stream>>>(W2, b2, W3, b3, W4, b4, v2, c);
    kC <<<451, NTHR, 0, stream>>>(W1, b1, v2, v1, c);
    kD <<<768, NTHR, 0, stream>>>(F, v1, sA, sB, NE, D);   // 3072 waves, ~6.5 rows/wave
    kE <<<(NTR + NTE + NTHR - 1) / NTHR, NTHR, 0, stream>>>(tr, te, sA, sB, c, out, NTR, NTE);
}

// Round 5
// 146.395 us; speedup vs baseline: 2.6410x; 1.4576x over previous
//
#include <hip/hip_runtime.h>
#include <math.h>

// Pair-embedding scorer; 4 stacked Linears, no activation => one affine map.
//   v4 = W4[:,0]; v3 = W3@v4; v2 = W2@v3; v1 = W1@v2
//   c  = b4 + b3.v4 + b2.v3 + b1.v2
//   sA[e] = feature[e] . v1[:901];  sB[e] = feature[e] . v1[901:]
//   out[i] = sigmoid(sA[p0] + sB[p1] + c)
//
// Round-3 lesson: cg grid.sync ~60us each -> plain launches.
// Round-4 lesson: per-block redundant v3 = 128 serial cold-load iterations
//   on 16 CUs = 75us latency chain. Shape every matvec as ONE WAVE PER ROW,
//   one memory round-trip per wave, full-grid parallelism.
//
// 5 launches: kA (v3, c init), kB (v2, c+=), kC (v1, c+=), kD (72MB stream),
// kE (head). c ordering is stream-ordered (each kernel's atomicAdd happens
// before the next launch reads it; kE is the only reader).
//
// ws layout (floats): [0,512) v3 | [512,1536) v2 | [1536,3338) v1 | [3400] c
//                     [4096,24096) sA | [24096,44096) sB

#define NTHR 256

__device__ inline float wave_reduce_sum(float v) {
    #pragma unroll
    for (int off = 32; off; off >>= 1) v += __shfl_down(v, off, 64);
    return v;
}

// ---- kA: v3 = W3@v4 (512 rows, K=64: one element/lane, ONE load/wave).
//      wave 512: c = b4 + b3.v4 ----
__global__ __launch_bounds__(NTHR)
void kA(const float* __restrict__ W3, const float* __restrict__ b3,
        const float* __restrict__ W4, const float* __restrict__ b4,
        float* __restrict__ v3, float* __restrict__ c) {
    const int tid = blockIdx.x * blockDim.x + threadIdx.x;
    const int gwave = tid >> 6, lane = tid & 63;
    if (gwave > 512) return;
    const float x = W4[lane];
    if (gwave == 512) {
        float acc = wave_reduce_sum(b3[lane] * x + ((lane == 0) ? *b4 : 0.f));
        if (lane == 0) *c = acc;
    } else {
        float acc = wave_reduce_sum(W3[(size_t)gwave * 64 + lane] * x);
        if (lane == 0) v3[gwave] = acc;
    }
}

// ---- kB: v2 = W2@v3 (1024 rows, K=512: 2 float4/lane); wave 1024: c += b2.v3 ----
__global__ __launch_bounds__(NTHR)
void kB(const float* __restrict__ W2, const float* __restrict__ b2,
        const float* __restrict__ v3, float* __restrict__ v2,
        float* __restrict__ c) {
    const int tid = blockIdx.x * blockDim.x + threadIdx.x;
    const int gwave = tid >> 6, lane = tid & 63;
    if (gwave > 1024) return;
    if (gwave == 1024) {
        const float4* b4p = (const float4*)b2;
        const float4* x4  = (const float4*)v3;
        float acc = 0.f;
        #pragma unroll
        for (int it = 0; it < 2; ++it) {
            float4 w = b4p[lane + 64 * it];
            float4 x = x4[lane + 64 * it];
            acc += w.x * x.x + w.y * x.y + w.z * x.z + w.w * x.w;
        }
        acc = wave_reduce_sum(acc);
        if (lane == 0) atomicAdd(c, acc);
        return;
    }
    const float4* row4 = (const float4*)(W2 + (size_t)gwave * 512);
    const float4* x4   = (const float4*)v3;
    float acc = 0.f;
    #pragma unroll
    for (int it = 0; it < 2; ++it) {
        float4 w = row4[lane + 64 * it];
        float4 x = x4[lane + 64 * it];
        acc += w.x * x.x + w.y * x.y + w.z * x.z + w.w * x.w;
    }
    acc = wave_reduce_sum(acc);
    if (lane == 0) v2[gwave] = acc;
}

// ---- kC: v1 = W1@v2 (1802 rows, K=1024: 4 float4/lane); wave 1802: c += b1.v2 ----
__global__ __launch_bounds__(NTHR)
void kC(const float* __restrict__ W1, const float* __restrict__ b1,
        const float* __restrict__ v2, float* __restrict__ v1,
        float* __restrict__ c) {
    const int tid = blockIdx.x * blockDim.x + threadIdx.x;
    const int gwave = tid >> 6, lane = tid & 63;
    if (gwave > 1802) return;
    const float4* row4 = (gwave == 1802) ? (const float4*)b1
                                         : (const float4*)(W1 + (size_t)gwave * 1024);
    const float4* x4 = (const float4*)v2;
    float acc = 0.f;
    #pragma unroll
    for (int it = 0; it < 4; ++it) {
        float4 w = row4[lane + 64 * it];
        float4 x = x4[lane + 64 * it];
        acc += w.x * x.x + w.y * x.y + w.z * x.z + w.w * x.w;
    }
    acc = wave_reduce_sum(acc);
    if (lane == 0) {
        if (gwave == 1802) atomicAdd(c, acc);
        else               v1[gwave] = acc;
    }
}

// ---- kD: per-entity half-dots over the 72 MB feature stream (float4).
// nwave % 4 == 0 and D % 4 == 1 -> per-wave alignment phase constant, so each
// lane's v1 coefficients are fixed; preload once into registers. ----
__global__ __launch_bounds__(NTHR)
void kD(const float* __restrict__ F, const float* __restrict__ v1,
        float* __restrict__ sA, float* __restrict__ sB, int NE, int D) {
    const int tid   = blockIdx.x * blockDim.x + threadIdx.x;
    const int gwave = tid >> 6, lane = tid & 63;
    const int nwave = (gridDim.x * blockDim.x) >> 6;
    const float* va = v1;
    const float* vb = v1 + D;
    const int a0   = (4 - (gwave & 3)) & 3;   // scalars to 16B boundary
    const int nvec = (D - a0) >> 2;
    const int rem  = (D - a0) & 3;

    float ca[16], cb[16];
    #pragma unroll
    for (int it = 0; it < 4; ++it) {
        int vi = lane + 64 * it;
        int d  = a0 + 4 * vi;
        bool ok = vi < nvec;
        ca[4*it+0] = ok ? va[d+0] : 0.f;  cb[4*it+0] = ok ? vb[d+0] : 0.f;
        ca[4*it+1] = ok ? va[d+1] : 0.f;  cb[4*it+1] = ok ? vb[d+1] : 0.f;
        ca[4*it+2] = ok ? va[d+2] : 0.f;  cb[4*it+2] = ok ? vb[d+2] : 0.f;
        ca[4*it+3] = ok ? va[d+3] : 0.f;  cb[4*it+3] = ok ? vb[d+3] : 0.f;
    }
    float cpa = (lane < a0) ? va[lane] : 0.f;
    float cpb = (lane < a0) ? vb[lane] : 0.f;
    int   dt  = a0 + 4 * nvec + lane;
    float cta = (lane < rem) ? va[dt] : 0.f;
    float ctb = (lane < rem) ? vb[dt] : 0.f;

    for (int row = gwave; row < NE; row += nwave) {
        const float* p = F + (size_t)row * (size_t)D;
        float a = 0.f, b = 0.f;
        if (lane < a0) { float f = p[lane]; a = f * cpa; b = f * cpb; }
        const float4* p4 = (const float4*)(p + a0);
        #pragma unroll
        for (int it = 0; it < 4; ++it) {
            int vi = lane + 64 * it;
            if (vi < nvec) {
                float4 f = p4[vi];
                a += f.x * ca[4*it+0] + f.y * ca[4*it+1]
                   + f.z * ca[4*it+2] + f.w * ca[4*it+3];
                b += f.x * cb[4*it+0] + f.y * cb[4*it+1]
                   + f.z * cb[4*it+2] + f.w * cb[4*it+3];
            }
        }
        if (lane < rem) { float f = p[a0 + 4 * nvec + lane]; a += f * cta; b += f * ctb; }
        a = wave_reduce_sum(a);
        b = wave_reduce_sum(b);
        if (lane == 0) { sA[row] = a; sB[row] = b; }
    }
}

// ---- kE: out[i] = sigmoid(sA[p0] + sB[p1] + c) ----
__global__ __launch_bounds__(NTHR)
void kE(const int* __restrict__ tr, const int* __restrict__ te,
        const float* __restrict__ sA, const float* __restrict__ sB,
        const float* __restrict__ c, float* __restrict__ out,
        int NTR, int NTE) {
    const int i = blockIdx.x * blockDim.x + threadIdx.x;
    const int n = NTR + NTE;
    if (i >= n) return;
    int2 pr;
    if (i < NTR) pr = ((const int2*)tr)[i];
    else         pr = ((const int2*)te)[i - NTR];
    float x = sA[pr.x] + sB[pr.y] + *c;      // sA/sB = 160 KB, L2-resident
    out[i] = 1.0f / (1.0f + __expf(-x));
}

extern "C" void kernel_launch(void* const* d_in, const int* in_sizes, int n_in,
                              void* d_out, int out_size, void* d_ws, size_t ws_size,
                              hipStream_t stream) {
    const float* F  = (const float*)d_in[0];
    const float* W1 = (const float*)d_in[1];
    const float* b1 = (const float*)d_in[2];
    const float* W2 = (const float*)d_in[3];
    const float* b2 = (const float*)d_in[4];
    const float* W3 = (const float*)d_in[5];
    const float* b3 = (const float*)d_in[6];
    const float* W4 = (const float*)d_in[7];
    const float* b4 = (const float*)d_in[8];
    const int*   tr = (const int*)d_in[9];
    const int*   te = (const int*)d_in[10];
    float*       out = (float*)d_out;
    float*       ws  = (float*)d_ws;

    const int NE = 20000, D = 901;
    const int NTR = in_sizes[9] / 2;    // 100000
    const int NTE = in_sizes[10] / 2;   // 25000

    float* v3 = ws;
    float* v2 = ws + 512;
    float* v1 = ws + 1536;
    float* c  = ws + 3400;
    float* sA = ws + 4096;
    float* sB = ws + 24096;

    kA<<<129, NTHR, 0, stream>>>(W3, b3, W4, b4, v3, c);          // 516 waves
    kB<<<257, NTHR, 0, stream>>>(W2, b2, v3, v2, c);              // 1028 waves
    kC<<<451, NTHR, 0, stream>>>(W1, b1, v2, v1, c);              // 1804 waves
    kD<<<768, NTHR, 0, stream>>>(F, v1, sA, sB, NE, D);           // 3072 waves
    kE<<<(NTR + NTE + NTHR - 1) / NTHR, NTHR, 0, stream>>>(tr, te, sA, sB, c, out, NTR, NTE);
}